// Round 4
// baseline (408.013 us; speedup 1.0000x reference)
//
#include <hip/hip_runtime.h>
#include <math.h>

// B=64, A=64, MULS=((64,0),(32,1),(16,2)) -> DIM_IN=240, NB=32, H=128, MOUT=112
#define H_ 128
#define NB_ 32

#define INV_STEP 3.1f
#define HALF_PI 1.57079632679489662f
#define INV_SQRT_NB 0.17677669529663689f
#define INV_SQRT_H 0.08838834764831845f
#define NORM0 0.125f
#define NORM1 0.10206207261596575f
#define NORM2 0.11180339887498948f
#define S3 1.7320508075688772f
#define S5 2.23606797749979f
#define S15 3.872983346207417f
#define LN2 0.6931471805599453f

typedef __attribute__((ext_vector_type(8))) short short8;
typedef __attribute__((ext_vector_type(4))) float f32x4;

// ---- big-mode ws layout: w2h @0 (32KB), w2l @32768, vfH @65536 (16MB), vfL after
#define VF_BYTES  16777216ull           // 64*64*2048 shorts * 2B
#define NEED_BIG  (65536ull + 2ull * VF_BYTES)   // 33,619,968
// ---- small-mode (round-3 fallback) ws layout: fp32 vecs @0 (18.9MB)
#define VECS_BYTES (64ull * 64 * 9 * 128 * 4)
#define NEED_SMALL VECS_BYTES

__device__ __forceinline__ float ssp_f(float x) {
    float t = 5.0f * x;
    float s = fmaxf(t, 0.0f) + __logf(1.0f + __expf(-fabsf(t)));
    return (s - LN2) * 0.2f;
}
__device__ __forceinline__ float sp_f(float x) {
    float t = 5.0f * x;
    float s = fmaxf(t, 0.0f) + __logf(1.0f + __expf(-fabsf(t)));
    return s * 0.2f;
}
__device__ __forceinline__ unsigned short f2bf(float x) {
    unsigned u = __float_as_uint(x);
    return (unsigned short)((u + 0x7FFFu + ((u >> 16) & 1u)) >> 16);
}
__device__ __forceinline__ float bf2f(unsigned short s) {
    return __uint_as_float(((unsigned)s) << 16);
}

// ===========================================================================
// BIG PATH
// ===========================================================================

// prep: fused  (a) per-(z,4b) V computation + bf16 hi/lo B-fragment emission,
//              (b) W2 -> B-fragment hi/lo split, (c) zero the accumulator.
// Grid: 1040 x 256.  Blocks [0,1024): V;  [1024,1040): W2 split.
__global__ __launch_bounds__(256, 2)
void prep_kernel(const float* __restrict__ rep, const float* __restrict__ W2,
                 const float* __restrict__ W3, float* __restrict__ accOut,
                 unsigned short* __restrict__ w2h, unsigned short* __restrict__ w2l,
                 unsigned short* __restrict__ vfH, unsigned short* __restrict__ vfL) {
    const int bx = blockIdx.x;
    const int tid = threadIdx.x;

    if (bx >= 1024) {   // ---- W2 fragment split (16 blocks) ----
        int pos0 = ((bx - 1024) * 256 + tid) * 4;
        #pragma unroll
        for (int t = 0; t < 4; ++t) {
            int pos = pos0 + t;
            int j = pos & 7, lane = (pos >> 3) & 63, fn = pos >> 9;
            int kt = fn >> 3, nt = fn & 7;
            int k = kt * 32 + (lane >> 4) * 8 + j;
            int n = nt * 16 + (lane & 15);
            float w = W2[k * 128 + n];
            unsigned short h = f2bf(w);
            w2h[pos] = h;
            w2l[pos] = f2bf(w - bf2f(h));
        }
        return;
    }

    const int z = bx >> 4, bq = bx & 15;
    if (bq == 0 && tid < 64) accOut[z * 64 + tid] = 0.0f;

    __shared__ __align__(16) float sRep[4 * 240];   // 3840 B
    __shared__ float sV[4 * 9 * 132];               // 19008 B

    for (int idx = tid; idx < 960; idx += 256)
        sRep[idx] = rep[((size_t)(z * 64 + bq * 4)) * 240 + idx];
    __syncthreads();

    // phase 1: V[b][cm][h] = sum_u W3[h][m]*rep_perm * (norm*inv_sqrt_H)
    #pragma unroll
    for (int sHalf = 0; sHalf < 2; ++sHalf) {
        const int s = tid + sHalf * 256;            // (h,b) slot
        const int b = s >> 7, h = s & 127;
        const float* w3r = W3 + (size_t)h * 112;
        const float* rr = sRep + b * 240;
        float a0 = 0.f, a1 = 0.f, a2 = 0.f, a3 = 0.f, a4 = 0.f,
              a5 = 0.f, a6 = 0.f, a7 = 0.f, a8 = 0.f;
        #pragma unroll 4
        for (int m4 = 0; m4 < 16; ++m4) {           // l=0
            float4 w = *reinterpret_cast<const float4*>(w3r + m4 * 4);
            const float* wp = reinterpret_cast<const float*>(&w);
            #pragma unroll
            for (int c = 0; c < 4; ++c) a0 = fmaf(wp[c], rr[m4 * 4 + c], a0);
        }
        #pragma unroll 2
        for (int u4 = 0; u4 < 8; ++u4) {            // l=1
            float4 w = *reinterpret_cast<const float4*>(w3r + 64 + u4 * 4);
            const float* wp = reinterpret_cast<const float*>(&w);
            #pragma unroll
            for (int c = 0; c < 4; ++c) {
                int u = u4 * 4 + c;
                a1 = fmaf(wp[c], rr[64 + 3 * u + 0], a1);
                a2 = fmaf(wp[c], rr[64 + 3 * u + 1], a2);
                a3 = fmaf(wp[c], rr[64 + 3 * u + 2], a3);
            }
        }
        #pragma unroll 2
        for (int u4 = 0; u4 < 4; ++u4) {            // l=2
            float4 w = *reinterpret_cast<const float4*>(w3r + 96 + u4 * 4);
            const float* wp = reinterpret_cast<const float*>(&w);
            #pragma unroll
            for (int c = 0; c < 4; ++c) {
                int u = u4 * 4 + c;
                a4 = fmaf(wp[c], rr[160 + 5 * u + 0], a4);
                a5 = fmaf(wp[c], rr[160 + 5 * u + 1], a5);
                a6 = fmaf(wp[c], rr[160 + 5 * u + 2], a6);
                a7 = fmaf(wp[c], rr[160 + 5 * u + 3], a7);
                a8 = fmaf(wp[c], rr[160 + 5 * u + 4], a8);
            }
        }
        const float n0 = NORM0 * INV_SQRT_H, n1 = NORM1 * INV_SQRT_H, n2 = NORM2 * INV_SQRT_H;
        float* vb = sV + b * 9 * 132;
        vb[0 * 132 + h] = a0 * n0;
        vb[1 * 132 + h] = a1 * n1;
        vb[2 * 132 + h] = a2 * n1;
        vb[3 * 132 + h] = a3 * n1;
        vb[4 * 132 + h] = a4 * n2;
        vb[5 * 132 + h] = a5 * n2;
        vb[6 * 132 + h] = a6 * n2;
        vb[7 * 132 + h] = a7 * n2;
        vb[8 * 132 + h] = a8 * n2;
    }
    __syncthreads();

    // phase 2: emit B-fragment-ordered bf16 hi/lo (coalesced 16B stores)
    #pragma unroll
    for (int q = 0; q < 4; ++q) {
        const int s = tid + q * 256;                // slot = (b,kt,lane)
        const int b = s >> 8, kt = (s >> 6) & 3, lane = s & 63;
        const int cm = lane & 15, quad = lane >> 4;
        const int hbase = kt * 32 + quad * 8;
        short8 hi8, lo8;
        #pragma unroll
        for (int j = 0; j < 8; ++j) {
            float v = (cm < 9) ? sV[(b * 9 + cm) * 132 + hbase + j] : 0.0f;
            unsigned short h = f2bf(v);
            hi8[j] = (short)h;
            lo8[j] = (short)f2bf(v - bf2f(h));
        }
        const size_t base = ((size_t)(z * 64 + bq * 4 + b)) * 2048 + (size_t)(kt * 64 + lane) * 8;
        *reinterpret_cast<short8*>(vfH + base) = hi8;
        *reinterpret_cast<short8*>(vfL + base) = lo8;
    }
}

// pair2: grid (16, 64): blockIdx.x = ta*4+tg, y = z. 256 thr = 4 waves.
// Block covers 16 a's x 16 b's (ordered pairs). Wave handles 2 b's per pass,
// 2 passes. Layer1 computed directly in MFMA A-frag layout (no LDS); layer2 =
// 3-way-split bf16 MFMA vs streamed W2 frags; H2 transposed through a
// wave-private LDS buffer into combine A-frags; combine = 12 MFMAs vs V frags;
// G-weighting + 16-lane shuffle reduce; LDS accumulate; one atomic per a.
__global__ __launch_bounds__(256, 4)
void pair2(const float* __restrict__ geom, const float* __restrict__ W1,
           const unsigned short* __restrict__ w2h, const unsigned short* __restrict__ w2l,
           const unsigned short* __restrict__ vfH, const unsigned short* __restrict__ vfL,
           float* __restrict__ accOut) {
    const int ta = blockIdx.x >> 2, tg = blockIdx.x & 3;
    const int z = blockIdx.y;
    const int tid = threadIdx.x;
    const int wv = tid >> 6, lane = tid & 63;
    const int m = lane & 15, quad = lane >> 4;

    __shared__ float sPos[96];                       // 16 a xyz | 16 b xyz
    __shared__ float sY[4][2][16][8];                // per-wave, per-pairIdx
    __shared__ __align__(16) float sH2w[4][16 * 132];// wave-private transpose buf
    __shared__ float sOut[16];

    if (tid < 48) sPos[tid] = geom[((size_t)z * 64 + ta * 16) * 3 + tid];
    else if (tid < 96) sPos[tid] = geom[((size_t)z * 64 + tg * 16) * 3 + (tid - 48)];
    if (tid < 16) sOut[tid] = 0.f;
    __syncthreads();

    const float ax = sPos[m * 3 + 0], ay = sPos[m * 3 + 1], az = sPos[m * 3 + 2];
    float* myH2 = &sH2w[wv][0];

    for (int it = 0; it < 2; ++it) {
        const int bi0 = it * 8 + wv * 2;             // two b's: bi0, bi0+1

        const float* w1p0[2];
        const float* w1p1[2];
        float c0v[2], c1v[2];

        #pragma unroll
        for (int p = 0; p < 2; ++p) {
            const int bi = bi0 + p;
            const float bxp = sPos[48 + bi * 3 + 0];
            const float byp = sPos[48 + bi * 3 + 1];
            const float bzp = sPos[48 + bi * 3 + 2];
            const float dx = ax - bxp, dy = ay - byp, dz = az - bzp;
            const float r2 = dx * dx + dy * dy + dz * dz;
            const float r = sqrtf(fmaxf(r2, 1e-12f));
            const float nz = (r2 > 1e-10f) ? 1.0f : 0.0f;
            const float ir = 1.0f / r;
            const float x = dx * ir, y = dy * ir, zz = dz * ir;
            if (quad == 0) {
                float4 g0, g1;
                g0.x = S3 * x * nz; g0.y = S3 * y * nz; g0.z = S3 * zz * nz;
                g0.w = S15 * x * y * nz;
                g1.x = S15 * y * zz * nz;
                g1.y = 0.5f * S5 * (3.0f * zz * zz - 1.0f) * nz;
                g1.z = S15 * x * zz * nz;
                g1.w = 0.5f * S15 * (x * x - y * y) * nz;
                *reinterpret_cast<float4*>(&sY[wv][p][m][0]) = g0;
                *reinterpret_cast<float4*>(&sY[wv][p][m][4]) = g1;
            }
            const float u = r * INV_STEP;
            int i0 = (int)floorf(u);
            const float d0 = u - (float)i0;
            float c0 = (i0 >= 0 && i0 < NB_) ? __cosf(HALF_PI * d0) : 0.f;
            const int i1 = i0 + 1;
            const float d1 = d0 - 1.0f;
            float c1 = (i1 >= 0 && i1 < NB_ && d1 > -1.0f) ? __cosf(HALF_PI * d1) : 0.f;
            const int i0c = min(max(i0, 0), NB_ - 1);
            const int i1c = min(max(i1, 0), NB_ - 1);
            w1p0[p] = W1 + i0c * H_;
            w1p1[p] = W1 + i1c * H_;
            c0v[p] = c0 * INV_SQRT_NB;
            c1v[p] = c1 * INV_SQRT_NB;
        }

        f32x4 acc[2][8];
        #pragma unroll
        for (int p = 0; p < 2; ++p)
            #pragma unroll
            for (int nt = 0; nt < 8; ++nt) {
                acc[p][nt][0] = 0.f; acc[p][nt][1] = 0.f;
                acc[p][nt][2] = 0.f; acc[p][nt][3] = 0.f;
            }

        // ---- layer1 (in A-frag regs) + layer2 MFMA ----
        #pragma unroll
        for (int kt = 0; kt < 4; ++kt) {
            const int koff = kt * 32 + quad * 8;
            short8 ah[2], al[2];
            #pragma unroll
            for (int p = 0; p < 2; ++p) {
                float4 wa0 = *reinterpret_cast<const float4*>(w1p0[p] + koff);
                float4 wa1 = *reinterpret_cast<const float4*>(w1p0[p] + koff + 4);
                float4 wb0 = *reinterpret_cast<const float4*>(w1p1[p] + koff);
                float4 wb1 = *reinterpret_cast<const float4*>(w1p1[p] + koff + 4);
                const float* a0p = reinterpret_cast<const float*>(&wa0);
                const float* a1p = reinterpret_cast<const float*>(&wa1);
                const float* b0p = reinterpret_cast<const float*>(&wb0);
                const float* b1p = reinterpret_cast<const float*>(&wb1);
                #pragma unroll
                for (int j = 0; j < 8; ++j) {
                    float w0 = (j < 4) ? a0p[j] : a1p[j - 4];
                    float w1v = (j < 4) ? b0p[j] : b1p[j - 4];
                    float xv = ssp_f(fmaf(c0v[p], w0, c1v[p] * w1v));
                    unsigned short h = f2bf(xv);
                    ah[p][j] = (short)h;
                    al[p][j] = (short)f2bf(xv - bf2f(h));
                }
            }
            const unsigned short* bhp = w2h + (size_t)(kt * 8) * 512 + (size_t)lane * 8;
            const unsigned short* blp = w2l + (size_t)(kt * 8) * 512 + (size_t)lane * 8;
            #pragma unroll
            for (int nt = 0; nt < 8; ++nt) {
                short8 bh = *reinterpret_cast<const short8*>(bhp + (size_t)nt * 512);
                short8 bl = *reinterpret_cast<const short8*>(blp + (size_t)nt * 512);
                acc[0][nt] = __builtin_amdgcn_mfma_f32_16x16x32_bf16(ah[0], bh, acc[0][nt], 0, 0, 0);
                acc[0][nt] = __builtin_amdgcn_mfma_f32_16x16x32_bf16(ah[0], bl, acc[0][nt], 0, 0, 0);
                acc[0][nt] = __builtin_amdgcn_mfma_f32_16x16x32_bf16(al[0], bh, acc[0][nt], 0, 0, 0);
                acc[1][nt] = __builtin_amdgcn_mfma_f32_16x16x32_bf16(ah[1], bh, acc[1][nt], 0, 0, 0);
                acc[1][nt] = __builtin_amdgcn_mfma_f32_16x16x32_bf16(ah[1], bl, acc[1][nt], 0, 0, 0);
                acc[1][nt] = __builtin_amdgcn_mfma_f32_16x16x32_bf16(al[1], bh, acc[1][nt], 0, 0, 0);
            }
        }

        // ---- per-b epilogue: ssp -> LDS transpose -> combine MFMA -> reduce ----
        #pragma unroll
        for (int p = 0; p < 2; ++p) {
            const int bglob = tg * 16 + bi0 + p;
            // H2 (C-layout) -> wave LDS [row=a][h], stride 132 (conflict-free)
            #pragma unroll
            for (int nt = 0; nt < 8; ++nt)
                #pragma unroll
                for (int reg = 0; reg < 4; ++reg)
                    myH2[(quad * 4 + reg) * 132 + nt * 16 + m] =
                        ssp_f(acc[p][nt][reg] * INV_SQRT_H);

            const unsigned short* vbh = vfH + ((size_t)z * 64 + bglob) * 2048 + (size_t)lane * 8;
            const unsigned short* vbl = vfL + ((size_t)z * 64 + bglob) * 2048 + (size_t)lane * 8;
            f32x4 T = {0.f, 0.f, 0.f, 0.f};
            #pragma unroll
            for (int kt = 0; kt < 4; ++kt) {
                const float* hrow = myH2 + m * 132 + kt * 32 + quad * 8;
                float4 q0 = *reinterpret_cast<const float4*>(hrow);
                float4 q1 = *reinterpret_cast<const float4*>(hrow + 4);
                const float* q0p = reinterpret_cast<const float*>(&q0);
                const float* q1p = reinterpret_cast<const float*>(&q1);
                short8 ah2, al2;
                #pragma unroll
                for (int j = 0; j < 8; ++j) {
                    float xv = (j < 4) ? q0p[j] : q1p[j - 4];
                    unsigned short h = f2bf(xv);
                    ah2[j] = (short)h;
                    al2[j] = (short)f2bf(xv - bf2f(h));
                }
                short8 bh = *reinterpret_cast<const short8*>(vbh + (size_t)kt * 512);
                short8 bl = *reinterpret_cast<const short8*>(vbl + (size_t)kt * 512);
                T = __builtin_amdgcn_mfma_f32_16x16x32_bf16(ah2, bh, T, 0, 0, 0);
                T = __builtin_amdgcn_mfma_f32_16x16x32_bf16(ah2, bl, T, 0, 0, 0);
                T = __builtin_amdgcn_mfma_f32_16x16x32_bf16(al2, bh, T, 0, 0, 0);
            }
            // G-weight: T C-layout col = lane&15 = cm, row = quad*4+reg = a
            const int cm = m;
            const int comp = min(max(cm - 1, 0), 7);
            float ps[4];
            #pragma unroll
            for (int reg = 0; reg < 4; ++reg) {
                const int row = quad * 4 + reg;
                float yv = sY[wv][p][row][comp];
                float g = (cm == 0) ? 1.0f : ((cm <= 8) ? yv : 0.0f);
                ps[reg] = T[reg] * g;
            }
            #pragma unroll
            for (int off = 1; off < 16; off <<= 1)
                #pragma unroll
                for (int reg = 0; reg < 4; ++reg)
                    ps[reg] += __shfl_xor(ps[reg], off);
            if (cm == 0) {
                #pragma unroll
                for (int reg = 0; reg < 4; ++reg)
                    atomicAdd(&sOut[quad * 4 + reg], ps[reg]);
            }
        }
    }
    __syncthreads();
    if (tid < 16) atomicAdd(&accOut[z * 64 + ta * 16 + tid], sOut[tid]);
}

// ===========================================================================
// SMALL PATH (round-3 fallback, proven)
// ===========================================================================
#define NPAIR 2080
#define PAIR_TILE 64
#define NTILE 33

__global__ void zero_out(float* __restrict__ out) {
    out[blockIdx.x * 256 + threadIdx.x] = 0.0f;
}

__global__ __launch_bounds__(256, 2)
void pv_small(const float* __restrict__ rep, const float* __restrict__ W3,
              float* __restrict__ vecs) {
    const int z = blockIdx.x;
    const int bh = blockIdx.y >> 1, hh = blockIdx.y & 1;
    const int tid = threadIdx.x;
    __shared__ __align__(16) float sF[32 * 240];
    __shared__ __align__(16) float sBT[112 * 64];
    const float* repz = rep + ((size_t)z * 64 + bh * 32) * 240;
    for (int idx = tid; idx < 1920; idx += 256) {
        int b = idx / 60, q = idx - b * 60, j0 = q * 4;
        float4 v = *reinterpret_cast<const float4*>(repz + b * 240 + j0);
        const float* vp = reinterpret_cast<const float*>(&v);
        #pragma unroll
        for (int c = 0; c < 4; ++c) {
            int j = j0 + c, pidx;
            if (j < 64) pidx = j;
            else if (j < 160) { int t = j - 64; int u = t / 3; int mm = t - u * 3; pidx = 64 + mm * 32 + u; }
            else { int t = j - 160; int u = t / 5; int mm = t - u * 5; pidx = 160 + mm * 16 + u; }
            sF[b * 240 + pidx] = vp[c];
        }
    }
    for (int idx = tid; idx < 1792; idx += 256) {
        int hp = idx / 28, q = idx - hp * 28, m0 = q * 4;
        float4 v = *reinterpret_cast<const float4*>(W3 + (size_t)(hh * 64 + hp) * 112 + m0);
        const float* vp = reinterpret_cast<const float*>(&v);
        #pragma unroll
        for (int c = 0; c < 4; ++c) {
            int mm = m0 + c;
            float nrm = (mm < 64) ? NORM0 : ((mm < 96) ? NORM1 : NORM2);
            sBT[mm * 64 + hp] = vp[c] * nrm;
        }
    }
    __syncthreads();
    const int b0 = (tid >> 5) * 4;
    const int h0 = (tid & 31) * 2;
    #pragma unroll
    for (int cm = 0; cm < 9; ++cm) {
        const int Aoff[9] = {0, 64, 96, 128, 160, 176, 192, 208, 224};
        const int Boff[9] = {0, 64, 64, 64, 96, 96, 96, 96, 96};
        const int Klen[9] = {64, 32, 32, 32, 16, 16, 16, 16, 16};
        const int ao = Aoff[cm], bo = Boff[cm], K = Klen[cm];
        float acc0[4] = {0.f, 0.f, 0.f, 0.f};
        float acc1[4] = {0.f, 0.f, 0.f, 0.f};
        for (int u = 0; u < K; u += 4) {
            float4 av[4];
            #pragma unroll
            for (int r = 0; r < 4; ++r)
                av[r] = *reinterpret_cast<const float4*>(sF + (b0 + r) * 240 + ao + u);
            #pragma unroll
            for (int uu = 0; uu < 4; ++uu) {
                float2 bv = *reinterpret_cast<const float2*>(sBT + (bo + u + uu) * 64 + h0);
                #pragma unroll
                for (int r = 0; r < 4; ++r) {
                    float a_ = reinterpret_cast<const float*>(&av[r])[uu];
                    acc0[r] = fmaf(a_, bv.x, acc0[r]);
                    acc1[r] = fmaf(a_, bv.y, acc1[r]);
                }
            }
        }
        #pragma unroll
        for (int r = 0; r < 4; ++r) {
            float2 st; st.x = acc0[r]; st.y = acc1[r];
            *reinterpret_cast<float2*>(vecs +
                (((size_t)z * 64 + bh * 32 + b0 + r) * 9 + cm) * 128 + hh * 64 + h0) = st;
        }
    }
}

__global__ __launch_bounds__(256, 4)
void pm_small(const float* __restrict__ geom, const float* __restrict__ W1,
              const float* __restrict__ W2,
              const float* __restrict__ vecs, float* __restrict__ accOut) {
    const int z = blockIdx.y;
    const int tid = threadIdx.x;
    __shared__ __align__(16) char sBigRaw[64 * 132 * 4];
    short* sAhi = reinterpret_cast<short*>(sBigRaw);
    short* sAlo = reinterpret_cast<short*>(sBigRaw + 16384);
    float* sH2  = reinterpret_cast<float*>(sBigRaw);
    __shared__ float sGeom[64 * 3];
    __shared__ int   sPA[PAIR_TILE], sPB[PAIR_TILE];
    __shared__ float sY1[PAIR_TILE][3], sY2[PAIR_TILE][5];
    __shared__ int   sI0[PAIR_TILE], sI1[PAIR_TILE];
    __shared__ float sC0[PAIR_TILE], sC1[PAIR_TILE];

    if (tid < 192) sGeom[tid] = geom[z * 192 + tid];
    if (tid < PAIR_TILE) {
        int p = blockIdx.x * PAIR_TILE + tid;
        int a = -1, b = 0;
        if (p < NPAIR) {
            int rem = p, aa = 0;
            while (rem >= 64 - aa) { rem -= 64 - aa; ++aa; }
            a = aa; b = aa + rem;
        }
        sPA[tid] = a; sPB[tid] = b;
    }
    __syncthreads();
    if (tid < PAIR_TILE) {
        int a = sPA[tid], b = sPB[tid];
        float dx = 0.f, dy = 0.f, dz = 0.f;
        if (a >= 0) {
            dx = sGeom[a * 3 + 0] - sGeom[b * 3 + 0];
            dy = sGeom[a * 3 + 1] - sGeom[b * 3 + 1];
            dz = sGeom[a * 3 + 2] - sGeom[b * 3 + 2];
        }
        float r2 = dx * dx + dy * dy + dz * dz;
        float r = sqrtf(fmaxf(r2, 1e-12f));
        float nz = (r2 > 1e-10f) ? 1.0f : 0.0f;
        float ir = 1.0f / r;
        float x = dx * ir, y = dy * ir, zz = dz * ir;
        sY1[tid][0] = S3 * x * nz;
        sY1[tid][1] = S3 * y * nz;
        sY1[tid][2] = S3 * zz * nz;
        sY2[tid][0] = S15 * x * y * nz;
        sY2[tid][1] = S15 * y * zz * nz;
        sY2[tid][2] = 0.5f * S5 * (3.0f * zz * zz - 1.0f) * nz;
        sY2[tid][3] = S15 * x * zz * nz;
        sY2[tid][4] = 0.5f * S15 * (x * x - y * y) * nz;
        float u = r * INV_STEP;
        int i0 = (int)floorf(u);
        float d0 = u - (float)i0;
        float c0 = (i0 >= 0 && i0 < NB_) ? __cosf(HALF_PI * d0) : 0.f;
        int i1 = i0 + 1;
        float d1 = d0 - 1.0f;
        float c1 = (i1 >= 0 && i1 < NB_ && d1 > -1.0f) ? __cosf(HALF_PI * d1) : 0.f;
        sI0[tid] = min(max(i0, 0), NB_ - 1); sC0[tid] = c0 * INV_SQRT_NB;
        sI1[tid] = min(max(i1, 0), NB_ - 1); sC1[tid] = c1 * INV_SQRT_NB;
    }
    __syncthreads();
    {
        const int pr = tid & 63, seg = tid >> 6;
        const float* w1r0 = W1 + sI0[pr] * H_;
        const float* w1r1 = W1 + sI1[pr] * H_;
        const float c0 = sC0[pr], c1 = sC1[pr];
        const int lane = seg * 16 + (pr & 15);
        const int g = pr >> 4;
        #pragma unroll
        for (int kt = 0; kt < 4; ++kt) {
            const int k0 = kt * 32 + seg * 8;
            float4 a0 = *reinterpret_cast<const float4*>(w1r0 + k0);
            float4 a1 = *reinterpret_cast<const float4*>(w1r0 + k0 + 4);
            float4 b0 = *reinterpret_cast<const float4*>(w1r1 + k0);
            float4 b1 = *reinterpret_cast<const float4*>(w1r1 + k0 + 4);
            const float* ap = reinterpret_cast<const float*>(&a0);
            const float* bp = reinterpret_cast<const float*>(&b0);
            short8 hi8, lo8;
            #pragma unroll
            for (int j = 0; j < 8; ++j) {
                float w0 = (j < 4) ? ap[j] : reinterpret_cast<const float*>(&a1)[j - 4];
                float w1v = (j < 4) ? bp[j] : reinterpret_cast<const float*>(&b1)[j - 4];
                float xv = ssp_f(c0 * w0 + c1 * w1v);
                unsigned short h = f2bf(xv);
                hi8[j] = (short)h;
                lo8[j] = (short)f2bf(xv - bf2f(h));
            }
            const int off = ((g * 4 + kt) * 64 + lane) * 8;
            *reinterpret_cast<short8*>(sAhi + off) = hi8;
            *reinterpret_cast<short8*>(sAlo + off) = lo8;
        }
    }
    __syncthreads();
    const int wv = tid >> 6;
    const int lane = tid & 63;
    f32x4 acc[8];
    #pragma unroll
    for (int nt = 0; nt < 8; ++nt) { acc[nt][0] = 0.f; acc[nt][1] = 0.f; acc[nt][2] = 0.f; acc[nt][3] = 0.f; }
    #pragma unroll
    for (int kt = 0; kt < 4; ++kt) {
        const int aoff = ((wv * 4 + kt) * 64 + lane) * 8;
        short8 ah = *reinterpret_cast<const short8*>(sAhi + aoff);
        short8 al = *reinterpret_cast<const short8*>(sAlo + aoff);
        #pragma unroll
        for (int nt = 0; nt < 8; ++nt) {
            short8 bh, bl;
            const int n = nt * 16 + (lane & 15);
            const int kb = kt * 32 + (lane >> 4) * 8;
            #pragma unroll
            for (int j = 0; j < 8; ++j) {
                float w = W2[(kb + j) * 128 + n];
                unsigned short h = f2bf(w);
                bh[j] = (short)h;
                bl[j] = (short)f2bf(w - bf2f(h));
            }
            acc[nt] = __builtin_amdgcn_mfma_f32_16x16x32_bf16(ah, bh, acc[nt], 0, 0, 0);
            acc[nt] = __builtin_amdgcn_mfma_f32_16x16x32_bf16(ah, bl, acc[nt], 0, 0, 0);
            acc[nt] = __builtin_amdgcn_mfma_f32_16x16x32_bf16(al, bh, acc[nt], 0, 0, 0);
        }
    }
    __syncthreads();
    {
        const int quad = lane >> 4, n15 = lane & 15;
        #pragma unroll
        for (int nt = 0; nt < 8; ++nt)
            #pragma unroll
            for (int reg = 0; reg < 4; ++reg) {
                const int row = wv * 16 + quad * 4 + reg;
                sH2[row * 132 + nt * 16 + n15] = ssp_f(acc[nt][reg] * INV_SQRT_H);
            }
    }
    __syncthreads();
    {
        const int rt = tid >> 5, ct = tid & 31;
        const int r0 = rt * 8, c0 = ct * 4;
        for (int r = 0; r < 8; ++r) {
            const int row = r0 + r;
            const int a = sPA[row], b = sPB[row];
            float ca = 0.f, cb = 0.f;
            if (a >= 0) {
                float4 hv = *reinterpret_cast<const float4*>(sH2 + row * 132 + c0);
                const float* hp = reinterpret_cast<const float*>(&hv);
                const float y10 = sY1[row][0], y11 = sY1[row][1], y12 = sY1[row][2];
                const float y20 = sY2[row][0], y21 = sY2[row][1], y22 = sY2[row][2],
                            y23 = sY2[row][3], y24 = sY2[row][4];
                const float* vb = vecs + ((size_t)(z * 64 + b) * 9) * 128 + c0;
                const float* va = vecs + ((size_t)(z * 64 + a) * 9) * 128 + c0;
                #pragma unroll
                for (int c = 0; c < 4; ++c) {
                    float ub = vb[c] + y10 * vb[128 + c] + y11 * vb[256 + c] + y12 * vb[384 + c]
                             + y20 * vb[512 + c] + y21 * vb[640 + c] + y22 * vb[768 + c]
                             + y23 * vb[896 + c] + y24 * vb[1024 + c];
                    float ua = va[c] - y10 * va[128 + c] - y11 * va[256 + c] - y12 * va[384 + c]
                             + y20 * va[512 + c] + y21 * va[640 + c] + y22 * va[768 + c]
                             + y23 * va[896 + c] + y24 * va[1024 + c];
                    ca = fmaf(hp[c], ub, ca);
                    cb = fmaf(hp[c], ua, cb);
                }
            }
            #pragma unroll
            for (int off = 16; off > 0; off >>= 1) {
                ca += __shfl_xor(ca, off);
                cb += __shfl_xor(cb, off);
            }
            if (ct == 0 && a >= 0) {
                atomicAdd(&accOut[z * 64 + a], ca * INV_SQRT_H);
                if (b != a) atomicAdd(&accOut[z * 64 + b], cb * INV_SQRT_H);
            }
        }
    }
}

// ---------------------------------------------------------------------------
__global__ __launch_bounds__(64, 8)
void finalize(float* __restrict__ out, const float* __restrict__ mask) {
    const int z = blockIdx.x, a = threadIdx.x;
    const float m = mask[z * 64 + a];
    float s = m;
    #pragma unroll
    for (int off = 32; off > 0; off >>= 1) s += __shfl_xor(s, off);
    const float inv = rsqrtf(s);
    const float v = out[z * 64 + a];
    out[z * 64 + a] = sp_f(v * inv) * m;
}

extern "C" void kernel_launch(void* const* d_in, const int* in_sizes, int n_in,
                              void* d_out, int out_size, void* d_ws, size_t ws_size,
                              hipStream_t stream) {
    const float* rep  = (const float*)d_in[0];
    const float* geom = (const float*)d_in[1];
    const float* mask = (const float*)d_in[2];
    const float* W1   = (const float*)d_in[3];
    const float* W2   = (const float*)d_in[4];
    const float* W3   = (const float*)d_in[5];
    float* out = (float*)d_out;

    if (ws_size >= NEED_BIG) {
        unsigned short* w2h = (unsigned short*)d_ws;
        unsigned short* w2l = (unsigned short*)((char*)d_ws + 32768);
        unsigned short* vfH = (unsigned short*)((char*)d_ws + 65536);
        unsigned short* vfL = (unsigned short*)((char*)d_ws + 65536 + VF_BYTES);
        prep_kernel<<<1040, 256, 0, stream>>>(rep, W2, W3, out, w2h, w2l, vfH, vfL);
        pair2<<<dim3(16, 64), 256, 0, stream>>>(geom, W1, w2h, w2l, vfH, vfL, out);
        finalize<<<64, 64, 0, stream>>>(out, mask);
    } else {
        float* vecs = (float*)d_ws;
        zero_out<<<16, 256, 0, stream>>>(out);
        pv_small<<<dim3(64, 4), 256, 0, stream>>>(rep, W3, vecs);
        pm_small<<<dim3(NTILE, 64), 256, 0, stream>>>(geom, W1, W2, vecs, out);
        finalize<<<64, 64, 0, stream>>>(out, mask);
    }
}

// Round 5
// 211.652 us; speedup vs baseline: 1.9278x; 1.9278x over previous
//
#include <hip/hip_runtime.h>
#include <math.h>

// B=64, A=64, MULS=((64,0),(32,1),(16,2)) -> DIM_IN=240, NB=32, H=128, MOUT=112
#define H_ 128
#define NB_ 32

#define INV_STEP 3.1f
#define HALF_PI 1.57079632679489662f
#define INV_SQRT_NB 0.17677669529663689f
#define INV_SQRT_H 0.08838834764831845f
#define NORM0 0.125f
#define NORM1 0.10206207261596575f
#define NORM2 0.11180339887498948f
#define S3 1.7320508075688772f
#define S5 2.23606797749979f
#define S15 3.872983346207417f
#define LN2 0.6931471805599453f

typedef __attribute__((ext_vector_type(8))) short short8;
typedef __attribute__((ext_vector_type(4))) float f32x4;

__device__ __forceinline__ float ssp_f(float x) {
    float t = 5.0f * x;
    float s = fmaxf(t, 0.0f) + __logf(1.0f + __expf(-fabsf(t)));
    return (s - LN2) * 0.2f;
}
__device__ __forceinline__ float sp_f(float x) {
    float t = 5.0f * x;
    float s = fmaxf(t, 0.0f) + __logf(1.0f + __expf(-fabsf(t)));
    return s * 0.2f;
}
__device__ __forceinline__ unsigned short f2bf(float x) {
    unsigned u = __float_as_uint(x);
    return (unsigned short)((u + 0x7FFFu + ((u >> 16) & 1u)) >> 16);
}
__device__ __forceinline__ float bf2f(unsigned short s) {
    return __uint_as_float(((unsigned)s) << 16);
}

// ---------------------------------------------------------------------------
// pair3: one block per (z, b-group of 8). Fused:
//   startup: V[8b][9cm][128h] from rep/W3 (fp32, LDS, norms folded);
//            W2 -> bf16 hi/lo MFMA-B-fragments (LDS, built once, read 8x);
//   main:    wave wv owns a-tile [16wv,16wv+16) x all 8 b (2 b per pass):
//            layer1 in A-frag registers -> 3-split bf16 MFMA layer2 ->
//            ssp -> wave-private LDS transpose -> 3-split MFMA combine
//            T[16a x 9cm] -> G-weight -> 16-lane shuffle reduce -> regs.
//   output:  partial[z][bg][a] to ws (written exactly once; no atomics).
// ---------------------------------------------------------------------------
__global__ __launch_bounds__(256, 1)
void pair3(const float* __restrict__ rep, const float* __restrict__ geom,
           const float* __restrict__ W1, const float* __restrict__ W2,
           const float* __restrict__ W3, float* __restrict__ partial) {
    const int bg = blockIdx.x;           // 0..7 -> b in [8bg, 8bg+8)
    const int z  = blockIdx.y;
    const int tid = threadIdx.x;
    const int wv = tid >> 6, lane = tid & 63;
    const int m = lane & 15, quad = lane >> 4;

    __shared__ __align__(16) short sW2h[16384];        // 32768 B
    __shared__ __align__(16) short sW2l[16384];        // 32768 B
    __shared__ __align__(16) float sV[8 * 9 * 132];    // 38016 B
    __shared__ __align__(16) float sH2w[4][16 * 133];  // 34048 B (also sRep @ startup)
    __shared__ float sPosA[192];
    __shared__ float sPosB[24];
    __shared__ __align__(16) float sYw[4][2][16][8];   // 4096 B

    float* sRep = &sH2w[0][0];   // 1920 floats, dead before main loop

    // ---- startup: stage geom + rep ----
    if (tid < 192) sPosA[tid] = geom[z * 192 + tid];
    else if (tid < 216) sPosB[tid - 192] = geom[((size_t)z * 64 + bg * 8) * 3 + (tid - 192)];
    {
        const float4* src = reinterpret_cast<const float4*>(rep + ((size_t)z * 64 + bg * 8) * 240);
        float4* dst = reinterpret_cast<float4*>(sRep);
        for (int i = tid; i < 480; i += 256) dst[i] = src[i];
    }
    __syncthreads();

    // ---- V compute: 1024 slots (b,h), thread does 4 ----
    #pragma unroll
    for (int i = 0; i < 4; ++i) {
        const int s = tid + i * 256;
        const int b = s >> 7, h = s & 127;
        const float* w3r = W3 + (size_t)h * 112;
        const float* rr = sRep + b * 240;
        float a0 = 0.f, a1 = 0.f, a2 = 0.f, a3 = 0.f, a4 = 0.f,
              a5 = 0.f, a6 = 0.f, a7 = 0.f, a8 = 0.f;
        #pragma unroll 4
        for (int m4 = 0; m4 < 16; ++m4) {            // l=0
            float4 w = *reinterpret_cast<const float4*>(w3r + m4 * 4);
            const float* wp = reinterpret_cast<const float*>(&w);
            #pragma unroll
            for (int c = 0; c < 4; ++c) a0 = fmaf(wp[c], rr[m4 * 4 + c], a0);
        }
        #pragma unroll 2
        for (int u4 = 0; u4 < 8; ++u4) {             // l=1
            float4 w = *reinterpret_cast<const float4*>(w3r + 64 + u4 * 4);
            const float* wp = reinterpret_cast<const float*>(&w);
            #pragma unroll
            for (int c = 0; c < 4; ++c) {
                int u = u4 * 4 + c;
                a1 = fmaf(wp[c], rr[64 + 3 * u + 0], a1);
                a2 = fmaf(wp[c], rr[64 + 3 * u + 1], a2);
                a3 = fmaf(wp[c], rr[64 + 3 * u + 2], a3);
            }
        }
        #pragma unroll 2
        for (int u4 = 0; u4 < 4; ++u4) {             // l=2
            float4 w = *reinterpret_cast<const float4*>(w3r + 96 + u4 * 4);
            const float* wp = reinterpret_cast<const float*>(&w);
            #pragma unroll
            for (int c = 0; c < 4; ++c) {
                int u = u4 * 4 + c;
                a4 = fmaf(wp[c], rr[160 + 5 * u + 0], a4);
                a5 = fmaf(wp[c], rr[160 + 5 * u + 1], a5);
                a6 = fmaf(wp[c], rr[160 + 5 * u + 2], a6);
                a7 = fmaf(wp[c], rr[160 + 5 * u + 3], a7);
                a8 = fmaf(wp[c], rr[160 + 5 * u + 4], a8);
            }
        }
        const float n0 = NORM0 * INV_SQRT_H, n1 = NORM1 * INV_SQRT_H, n2 = NORM2 * INV_SQRT_H;
        float* vb = sV + b * 9 * 132;
        vb[0 * 132 + h] = a0 * n0;
        vb[1 * 132 + h] = a1 * n1;
        vb[2 * 132 + h] = a2 * n1;
        vb[3 * 132 + h] = a3 * n1;
        vb[4 * 132 + h] = a4 * n2;
        vb[5 * 132 + h] = a5 * n2;
        vb[6 * 132 + h] = a6 * n2;
        vb[7 * 132 + h] = a7 * n2;
        vb[8 * 132 + h] = a8 * n2;
    }

    // ---- W2 -> LDS bf16 hi/lo fragments (coalesced global reads) ----
    #pragma unroll 4
    for (int i = 0; i < 64; ++i) {
        const int idx = i * 256 + tid;               // row-major W2 index
        const int k = idx >> 7, n = idx & 127;
        const float w = W2[idx];
        const int kt = k >> 5, q8 = (k >> 3) & 3, j = k & 7;
        const int nt = n >> 4, mm = n & 15;
        const int pos = ((kt * 8 + nt) * 64 + q8 * 16 + mm) * 8 + j;
        const unsigned short hh = f2bf(w);
        sW2h[pos] = (short)hh;
        sW2l[pos] = (short)f2bf(w - bf2f(hh));
    }
    __syncthreads();   // sRep (in sH2w) dead from here on

    // ---- main loop: a-tile = wv, 4 passes x 2 b ----
    const int aLoc = wv * 16 + m;
    const float ax = sPosA[aLoc * 3 + 0];
    const float ay = sPosA[aLoc * 3 + 1];
    const float az = sPosA[aLoc * 3 + 2];
    float* myH2 = &sH2w[wv][0];
    float outAcc[4] = {0.f, 0.f, 0.f, 0.f};

    for (int pass = 0; pass < 4; ++pass) {
        const float* w1p0[2];
        const float* w1p1[2];
        float c0v[2], c1v[2];

        #pragma unroll
        for (int p = 0; p < 2; ++p) {
            const int bl = pass * 2 + p;
            const float bx = sPosB[bl * 3 + 0];
            const float by = sPosB[bl * 3 + 1];
            const float bz = sPosB[bl * 3 + 2];
            const float dx = ax - bx, dy = ay - by, dz = az - bz;
            const float r2 = dx * dx + dy * dy + dz * dz;
            const float r = sqrtf(fmaxf(r2, 1e-12f));
            const float nzf = (r2 > 1e-10f) ? 1.0f : 0.0f;
            const float ir = 1.0f / r;
            const float x = dx * ir, y = dy * ir, zz = dz * ir;
            if (quad == 0) {
                float4 g0, g1;
                g0.x = S3 * x * nzf; g0.y = S3 * y * nzf; g0.z = S3 * zz * nzf;
                g0.w = S15 * x * y * nzf;
                g1.x = S15 * y * zz * nzf;
                g1.y = 0.5f * S5 * (3.0f * zz * zz - 1.0f) * nzf;
                g1.z = S15 * x * zz * nzf;
                g1.w = 0.5f * S15 * (x * x - y * y) * nzf;
                *reinterpret_cast<float4*>(&sYw[wv][p][m][0]) = g0;
                *reinterpret_cast<float4*>(&sYw[wv][p][m][4]) = g1;
            }
            const float u = r * INV_STEP;
            int i0 = (int)floorf(u);
            const float d0 = u - (float)i0;
            float c0 = (i0 >= 0 && i0 < NB_) ? __cosf(HALF_PI * d0) : 0.f;
            const int i1 = i0 + 1;
            const float d1 = d0 - 1.0f;
            float c1 = (i1 >= 0 && i1 < NB_ && d1 > -1.0f) ? __cosf(HALF_PI * d1) : 0.f;
            const int i0c = min(max(i0, 0), NB_ - 1);
            const int i1c = min(max(i1, 0), NB_ - 1);
            w1p0[p] = W1 + i0c * H_;
            w1p1[p] = W1 + i1c * H_;
            c0v[p] = c0 * INV_SQRT_NB;
            c1v[p] = c1 * INV_SQRT_NB;
        }

        f32x4 acc[2][8];
        #pragma unroll
        for (int p = 0; p < 2; ++p)
            #pragma unroll
            for (int nt = 0; nt < 8; ++nt) {
                acc[p][nt][0] = 0.f; acc[p][nt][1] = 0.f;
                acc[p][nt][2] = 0.f; acc[p][nt][3] = 0.f;
            }

        // ---- layer1 (A-frag regs) + layer2 MFMA (W2 frags from LDS) ----
        #pragma unroll
        for (int kt = 0; kt < 4; ++kt) {
            const int koff = kt * 32 + quad * 8;
            short8 ah[2], al[2];
            #pragma unroll
            for (int p = 0; p < 2; ++p) {
                float4 wa0 = *reinterpret_cast<const float4*>(w1p0[p] + koff);
                float4 wa1 = *reinterpret_cast<const float4*>(w1p0[p] + koff + 4);
                float4 wb0 = *reinterpret_cast<const float4*>(w1p1[p] + koff);
                float4 wb1 = *reinterpret_cast<const float4*>(w1p1[p] + koff + 4);
                const float* a0p = reinterpret_cast<const float*>(&wa0);
                const float* a1p = reinterpret_cast<const float*>(&wa1);
                const float* b0p = reinterpret_cast<const float*>(&wb0);
                const float* b1p = reinterpret_cast<const float*>(&wb1);
                #pragma unroll
                for (int j = 0; j < 8; ++j) {
                    float w0 = (j < 4) ? a0p[j] : a1p[j - 4];
                    float w1v = (j < 4) ? b0p[j] : b1p[j - 4];
                    float xv = ssp_f(fmaf(c0v[p], w0, c1v[p] * w1v));
                    unsigned short h = f2bf(xv);
                    ah[p][j] = (short)h;
                    al[p][j] = (short)f2bf(xv - bf2f(h));
                }
            }
            const short* bhp = sW2h + (size_t)(kt * 8) * 512 + (size_t)lane * 8;
            const short* blp = sW2l + (size_t)(kt * 8) * 512 + (size_t)lane * 8;
            #pragma unroll
            for (int nt = 0; nt < 8; ++nt) {
                short8 bh = *reinterpret_cast<const short8*>(bhp + nt * 512);
                short8 bl = *reinterpret_cast<const short8*>(blp + nt * 512);
                acc[0][nt] = __builtin_amdgcn_mfma_f32_16x16x32_bf16(ah[0], bh, acc[0][nt], 0, 0, 0);
                acc[0][nt] = __builtin_amdgcn_mfma_f32_16x16x32_bf16(ah[0], bl, acc[0][nt], 0, 0, 0);
                acc[0][nt] = __builtin_amdgcn_mfma_f32_16x16x32_bf16(al[0], bh, acc[0][nt], 0, 0, 0);
                acc[1][nt] = __builtin_amdgcn_mfma_f32_16x16x32_bf16(ah[1], bh, acc[1][nt], 0, 0, 0);
                acc[1][nt] = __builtin_amdgcn_mfma_f32_16x16x32_bf16(ah[1], bl, acc[1][nt], 0, 0, 0);
                acc[1][nt] = __builtin_amdgcn_mfma_f32_16x16x32_bf16(al[1], bh, acc[1][nt], 0, 0, 0);
            }
        }

        // ---- per-b epilogue ----
        #pragma unroll
        for (int p = 0; p < 2; ++p) {
            const int bl = pass * 2 + p;
            // ssp + transpose through wave-private LDS (stride 133)
            #pragma unroll
            for (int nt = 0; nt < 8; ++nt)
                #pragma unroll
                for (int reg = 0; reg < 4; ++reg)
                    myH2[(quad * 4 + reg) * 133 + nt * 16 + m] =
                        ssp_f(acc[p][nt][reg] * INV_SQRT_H);

            const int cmc = min(m, 8);
            f32x4 T0 = {0.f, 0.f, 0.f, 0.f};
            f32x4 T1 = {0.f, 0.f, 0.f, 0.f};
            #pragma unroll
            for (int kt = 0; kt < 4; ++kt) {
                const float* hr = myH2 + m * 133 + kt * 32 + quad * 8;
                short8 ah2, al2;
                #pragma unroll
                for (int j = 0; j < 8; ++j) {
                    float xv = hr[j];
                    unsigned short h = f2bf(xv);
                    ah2[j] = (short)h;
                    al2[j] = (short)f2bf(xv - bf2f(h));
                }
                const float* vr = sV + (size_t)(bl * 9 + cmc) * 132 + kt * 32 + quad * 8;
                float4 v0 = *reinterpret_cast<const float4*>(vr);
                float4 v1 = *reinterpret_cast<const float4*>(vr + 4);
                const float* v0p = reinterpret_cast<const float*>(&v0);
                const float* v1p = reinterpret_cast<const float*>(&v1);
                short8 bh2, bl2;
                #pragma unroll
                for (int j = 0; j < 8; ++j) {
                    float vv = (j < 4) ? v0p[j] : v1p[j - 4];
                    unsigned short h = f2bf(vv);
                    bh2[j] = (short)h;
                    bl2[j] = (short)f2bf(vv - bf2f(h));
                }
                if (kt & 1) {
                    T1 = __builtin_amdgcn_mfma_f32_16x16x32_bf16(ah2, bh2, T1, 0, 0, 0);
                    T1 = __builtin_amdgcn_mfma_f32_16x16x32_bf16(ah2, bl2, T1, 0, 0, 0);
                    T1 = __builtin_amdgcn_mfma_f32_16x16x32_bf16(al2, bh2, T1, 0, 0, 0);
                } else {
                    T0 = __builtin_amdgcn_mfma_f32_16x16x32_bf16(ah2, bh2, T0, 0, 0, 0);
                    T0 = __builtin_amdgcn_mfma_f32_16x16x32_bf16(ah2, bl2, T0, 0, 0, 0);
                    T0 = __builtin_amdgcn_mfma_f32_16x16x32_bf16(al2, bh2, T0, 0, 0, 0);
                }
            }

            // G-weight (T C-layout: col=lane&15=cm, row=quad*4+reg=a-local)
            const int comp = (m >= 1 && m <= 8) ? (m - 1) : 0;
            float ps[4];
            #pragma unroll
            for (int reg = 0; reg < 4; ++reg) {
                const int row = quad * 4 + reg;
                const float Tv = T0[reg] + T1[reg];
                const float yv = sYw[wv][p][row][comp];
                const float g = (m == 0) ? 1.0f : ((m <= 8) ? yv : 0.0f);
                ps[reg] = Tv * g;
            }
            #pragma unroll
            for (int off = 1; off < 16; off <<= 1)
                #pragma unroll
                for (int reg = 0; reg < 4; ++reg)
                    ps[reg] += __shfl_xor(ps[reg], off);
            #pragma unroll
            for (int reg = 0; reg < 4; ++reg) outAcc[reg] += ps[reg];
        }
    }

    // ---- write partial[z][bg][a]: lanes m==0 hold a = wv*16 + quad*4 + reg ----
    if (m == 0) {
        float4 st;
        st.x = outAcc[0]; st.y = outAcc[1]; st.z = outAcc[2]; st.w = outAcc[3];
        *reinterpret_cast<float4*>(partial + ((size_t)(z * 8 + bg)) * 64 + wv * 16 + quad * 4) = st;
    }
}

// ---------------------------------------------------------------------------
// finalize: out[z,a] = sp( (sum_bg partial) / sqrt(n_atoms) ) * mask
// ---------------------------------------------------------------------------
__global__ __launch_bounds__(64, 8)
void finalize(const float* __restrict__ partial, const float* __restrict__ mask,
              float* __restrict__ out) {
    const int z = blockIdx.x, a = threadIdx.x;
    const float mk = mask[z * 64 + a];
    float s = mk;
    #pragma unroll
    for (int off = 32; off > 0; off >>= 1) s += __shfl_xor(s, off);
    const float inv = rsqrtf(s);
    float acc = 0.f;
    #pragma unroll
    for (int bg = 0; bg < 8; ++bg)
        acc += partial[((size_t)(z * 8 + bg)) * 64 + a];
    out[z * 64 + a] = sp_f(acc * inv) * mk;
}

extern "C" void kernel_launch(void* const* d_in, const int* in_sizes, int n_in,
                              void* d_out, int out_size, void* d_ws, size_t ws_size,
                              hipStream_t stream) {
    const float* rep  = (const float*)d_in[0];
    const float* geom = (const float*)d_in[1];
    const float* mask = (const float*)d_in[2];
    const float* W1   = (const float*)d_in[3];
    const float* W2   = (const float*)d_in[4];
    const float* W3   = (const float*)d_in[5];
    float* out = (float*)d_out;
    float* partial = (float*)d_ws;   // 512*64 floats = 128 KB

    pair3<<<dim3(8, 64), 256, 0, stream>>>(rep, geom, W1, W2, W3, partial);
    finalize<<<64, 64, 0, stream>>>(partial, mask, out);
}

// Round 6
// 138.992 us; speedup vs baseline: 2.9355x; 1.5228x over previous
//
#include <hip/hip_runtime.h>
#include <math.h>

// B=64, A=64, MULS=((64,0),(32,1),(16,2)) -> DIM_IN=240, NB=32, H=128, MOUT=112
#define H_ 128
#define NB_ 32

#define INV_STEP 3.1f
#define HALF_PI 1.57079632679489662f
#define INV_SQRT_NB 0.17677669529663689f
#define INV_SQRT_H 0.08838834764831845f
#define NORM0 0.125f
#define NORM1 0.10206207261596575f
#define NORM2 0.11180339887498948f
#define S3 1.7320508075688772f
#define S5 2.23606797749979f
#define S15 3.872983346207417f
#define LN2 0.6931471805599453f

typedef __attribute__((ext_vector_type(8))) _Float16 half8;
typedef __attribute__((ext_vector_type(4))) float f32x4;

__device__ __forceinline__ float ssp_f(float x) {
    float t = 5.0f * x;
    float s = fmaxf(t, 0.0f) + __logf(1.0f + __expf(-fabsf(t)));
    return (s - LN2) * 0.2f;
}
__device__ __forceinline__ float sp_f(float x) {
    float t = 5.0f * x;
    float s = fmaxf(t, 0.0f) + __logf(1.0f + __expf(-fabsf(t)));
    return s * 0.2f;
}

// ---------------------------------------------------------------------------
// w2half: W2 (fp32 row-major) -> fp16 MFMA-B-fragment order in ws.
// pos = ((kt*8+nt)*64 + lane)*8 + j ; k = kt*32+(lane>>4)*8+j ; n = nt*16+(lane&15)
// ---------------------------------------------------------------------------
__global__ void w2half(const float* __restrict__ W2, _Float16* __restrict__ w2f) {
    const int e0 = (blockIdx.x * 256 + threadIdx.x) * 4;
    #pragma unroll
    for (int t = 0; t < 4; ++t) {
        const int pos = e0 + t;
        const int j = pos & 7, lane = (pos >> 3) & 63, fn = pos >> 9;
        const int kt = fn >> 3, nt = fn & 7;
        const int k = kt * 32 + (lane >> 4) * 8 + j;
        const int n = nt * 16 + (lane & 15);
        w2f[pos] = (_Float16)W2[k * 128 + n];
    }
}

// ---------------------------------------------------------------------------
// pair4: one block per (z, 8-b-group); 2 blocks/CU (LDS ~72 KB).
//   startup: V[8b] computed from rep/W3 in fp32 regs, emitted as fp16
//            MFMA-B-fragments in LDS (norms*inv_sqrt_H folded).
//   main: wave wv owns a-tile [16wv,16wv+16) x all 8 b (2 b per pass):
//     layer1 in fp16 A-frag registers -> fp16 MFMA layer2 (W2 frags from
//     L1/L2 via ws) -> ssp -> wave-private LDS transpose -> fp16 MFMA
//     combine vs V frags -> G-weight -> 16-lane shuffle reduce.
//   output: partial[z][bg][a] (written exactly once; no atomics).
// ---------------------------------------------------------------------------
__global__ __launch_bounds__(256, 2)
void pair4(const float* __restrict__ rep, const float* __restrict__ geom,
           const float* __restrict__ W1, const float* __restrict__ W3,
           const _Float16* __restrict__ w2f, float* __restrict__ partial) {
    const int bg = blockIdx.x;           // b in [8bg, 8bg+8)
    const int z  = blockIdx.y;
    const int tid = threadIdx.x;
    const int wv = tid >> 6, lane = tid & 63;
    const int m = lane & 15, quad = lane >> 4;

    __shared__ __align__(16) _Float16 sVf[16384];      // 32768 B  [b][kt][lane][j]
    __shared__ __align__(16) float sH2w[4][16 * 133];  // 34048 B (sRep alias @startup)
    __shared__ float sPosA[192];
    __shared__ float sPosB[24];
    __shared__ __align__(16) float sYw[4][2][16][8];   // 4096 B

    float* sRep = &sH2w[0][0];   // 1920 floats, dead before main loop

    // ---- startup: stage geom + rep ----
    if (tid < 192) sPosA[tid] = geom[z * 192 + tid];
    else if (tid < 216) sPosB[tid - 192] = geom[((size_t)z * 64 + bg * 8) * 3 + (tid - 192)];
    {
        const float4* src = reinterpret_cast<const float4*>(rep + ((size_t)z * 64 + bg * 8) * 240);
        float4* dst = reinterpret_cast<float4*>(sRep);
        for (int i = tid; i < 480; i += 256) dst[i] = src[i];
    }
    __syncthreads();

    // ---- V compute: 1024 slots (b,h); emit fp16 B-frags (16 n's incl. zeros) ----
    #pragma unroll
    for (int i = 0; i < 4; ++i) {
        const int s = tid + i * 256;
        const int b = s >> 7, h = s & 127;
        const float* w3r = W3 + (size_t)h * 112;
        const float* rr = sRep + b * 240;
        float a0 = 0.f, a1 = 0.f, a2 = 0.f, a3 = 0.f, a4 = 0.f,
              a5 = 0.f, a6 = 0.f, a7 = 0.f, a8 = 0.f;
        #pragma unroll 4
        for (int m4 = 0; m4 < 16; ++m4) {            // l=0
            float4 w = *reinterpret_cast<const float4*>(w3r + m4 * 4);
            const float* wp = reinterpret_cast<const float*>(&w);
            #pragma unroll
            for (int c = 0; c < 4; ++c) a0 = fmaf(wp[c], rr[m4 * 4 + c], a0);
        }
        #pragma unroll 2
        for (int u4 = 0; u4 < 8; ++u4) {             // l=1
            float4 w = *reinterpret_cast<const float4*>(w3r + 64 + u4 * 4);
            const float* wp = reinterpret_cast<const float*>(&w);
            #pragma unroll
            for (int c = 0; c < 4; ++c) {
                int u = u4 * 4 + c;
                a1 = fmaf(wp[c], rr[64 + 3 * u + 0], a1);
                a2 = fmaf(wp[c], rr[64 + 3 * u + 1], a2);
                a3 = fmaf(wp[c], rr[64 + 3 * u + 2], a3);
            }
        }
        #pragma unroll 2
        for (int u4 = 0; u4 < 4; ++u4) {             // l=2
            float4 w = *reinterpret_cast<const float4*>(w3r + 96 + u4 * 4);
            const float* wp = reinterpret_cast<const float*>(&w);
            #pragma unroll
            for (int c = 0; c < 4; ++c) {
                int u = u4 * 4 + c;
                a4 = fmaf(wp[c], rr[160 + 5 * u + 0], a4);
                a5 = fmaf(wp[c], rr[160 + 5 * u + 1], a5);
                a6 = fmaf(wp[c], rr[160 + 5 * u + 2], a6);
                a7 = fmaf(wp[c], rr[160 + 5 * u + 3], a7);
                a8 = fmaf(wp[c], rr[160 + 5 * u + 4], a8);
            }
        }
        const float n0 = NORM0 * INV_SQRT_H, n1 = NORM1 * INV_SQRT_H, n2 = NORM2 * INV_SQRT_H;
        float vals[9];
        vals[0] = a0 * n0;
        vals[1] = a1 * n1; vals[2] = a2 * n1; vals[3] = a3 * n1;
        vals[4] = a4 * n2; vals[5] = a5 * n2; vals[6] = a6 * n2;
        vals[7] = a7 * n2; vals[8] = a8 * n2;
        // h = kt*32 + qd*8 + j ; frag pos = (b*4+kt)*512 + (qd*16+n)*8 + j
        const int kt = h >> 5, qd = (h >> 3) & 3, j = h & 7;
        _Float16* base = sVf + (b * 4 + kt) * 512 + qd * 128 + j;
        #pragma unroll
        for (int n = 0; n < 16; ++n)
            base[n * 8] = (n < 9) ? (_Float16)vals[n] : (_Float16)0.0f;
    }
    __syncthreads();   // sVf ready; sRep (in sH2w) dead from here on

    // ---- main loop ----
    const int aLoc = wv * 16 + m;
    const float ax = sPosA[aLoc * 3 + 0];
    const float ay = sPosA[aLoc * 3 + 1];
    const float az = sPosA[aLoc * 3 + 2];
    float* myH2 = &sH2w[wv][0];
    float outAcc[4] = {0.f, 0.f, 0.f, 0.f};

    for (int pass = 0; pass < 4; ++pass) {
        const float* w1p0[2];
        const float* w1p1[2];
        float c0v[2], c1v[2];

        #pragma unroll
        for (int p = 0; p < 2; ++p) {
            const int bl = pass * 2 + p;
            const float bx = sPosB[bl * 3 + 0];
            const float by = sPosB[bl * 3 + 1];
            const float bz = sPosB[bl * 3 + 2];
            const float dx = ax - bx, dy = ay - by, dz = az - bz;
            const float r2 = dx * dx + dy * dy + dz * dz;
            const float r = sqrtf(fmaxf(r2, 1e-12f));
            const float nzf = (r2 > 1e-10f) ? 1.0f : 0.0f;
            const float ir = 1.0f / r;
            const float x = dx * ir, y = dy * ir, zz = dz * ir;
            if (quad == 0) {
                float4 g0, g1;
                g0.x = S3 * x * nzf; g0.y = S3 * y * nzf; g0.z = S3 * zz * nzf;
                g0.w = S15 * x * y * nzf;
                g1.x = S15 * y * zz * nzf;
                g1.y = 0.5f * S5 * (3.0f * zz * zz - 1.0f) * nzf;
                g1.z = S15 * x * zz * nzf;
                g1.w = 0.5f * S15 * (x * x - y * y) * nzf;
                *reinterpret_cast<float4*>(&sYw[wv][p][m][0]) = g0;
                *reinterpret_cast<float4*>(&sYw[wv][p][m][4]) = g1;
            }
            const float u = r * INV_STEP;
            int i0 = (int)floorf(u);
            const float d0 = u - (float)i0;
            float c0 = (i0 >= 0 && i0 < NB_) ? __cosf(HALF_PI * d0) : 0.f;
            const int i1 = i0 + 1;
            const float d1 = d0 - 1.0f;
            float c1 = (i1 >= 0 && i1 < NB_ && d1 > -1.0f) ? __cosf(HALF_PI * d1) : 0.f;
            const int i0c = min(max(i0, 0), NB_ - 1);
            const int i1c = min(max(i1, 0), NB_ - 1);
            w1p0[p] = W1 + i0c * H_;
            w1p1[p] = W1 + i1c * H_;
            c0v[p] = c0 * INV_SQRT_NB;
            c1v[p] = c1 * INV_SQRT_NB;
        }

        f32x4 acc[2][8];
        #pragma unroll
        for (int p = 0; p < 2; ++p)
            #pragma unroll
            for (int nt = 0; nt < 8; ++nt) {
                acc[p][nt][0] = 0.f; acc[p][nt][1] = 0.f;
                acc[p][nt][2] = 0.f; acc[p][nt][3] = 0.f;
            }

        // ---- layer1 (fp16 A-frag regs) + layer2 fp16 MFMA (W2 frags via L1) ----
        #pragma unroll
        for (int kt = 0; kt < 4; ++kt) {
            const int koff = kt * 32 + quad * 8;
            half8 ah[2];
            #pragma unroll
            for (int p = 0; p < 2; ++p) {
                float4 wa0 = *reinterpret_cast<const float4*>(w1p0[p] + koff);
                float4 wa1 = *reinterpret_cast<const float4*>(w1p0[p] + koff + 4);
                float4 wb0 = *reinterpret_cast<const float4*>(w1p1[p] + koff);
                float4 wb1 = *reinterpret_cast<const float4*>(w1p1[p] + koff + 4);
                const float* a0p = reinterpret_cast<const float*>(&wa0);
                const float* a1p = reinterpret_cast<const float*>(&wa1);
                const float* b0p = reinterpret_cast<const float*>(&wb0);
                const float* b1p = reinterpret_cast<const float*>(&wb1);
                #pragma unroll
                for (int j = 0; j < 8; ++j) {
                    float w0 = (j < 4) ? a0p[j] : a1p[j - 4];
                    float w1v = (j < 4) ? b0p[j] : b1p[j - 4];
                    ah[p][j] = (_Float16)ssp_f(fmaf(c0v[p], w0, c1v[p] * w1v));
                }
            }
            const _Float16* bhp = w2f + (size_t)(kt * 8) * 512 + (size_t)lane * 8;
            #pragma unroll
            for (int nt = 0; nt < 8; ++nt) {
                half8 bh = *reinterpret_cast<const half8*>(bhp + nt * 512);
                acc[0][nt] = __builtin_amdgcn_mfma_f32_16x16x32_f16(ah[0], bh, acc[0][nt], 0, 0, 0);
                acc[1][nt] = __builtin_amdgcn_mfma_f32_16x16x32_f16(ah[1], bh, acc[1][nt], 0, 0, 0);
            }
        }

        // ---- per-b epilogue ----
        #pragma unroll
        for (int p = 0; p < 2; ++p) {
            const int bl = pass * 2 + p;
            // ssp + transpose through wave-private LDS (fp32, stride 133)
            #pragma unroll
            for (int nt = 0; nt < 8; ++nt)
                #pragma unroll
                for (int reg = 0; reg < 4; ++reg)
                    myH2[(quad * 4 + reg) * 133 + nt * 16 + m] =
                        ssp_f(acc[p][nt][reg] * INV_SQRT_H);

            f32x4 T0 = {0.f, 0.f, 0.f, 0.f};
            f32x4 T1 = {0.f, 0.f, 0.f, 0.f};
            #pragma unroll
            for (int kt = 0; kt < 4; ++kt) {
                const float* hr = myH2 + m * 133 + kt * 32 + quad * 8;
                float4 q0 = *reinterpret_cast<const float4*>(hr);
                float4 q1 = *reinterpret_cast<const float4*>(hr + 4);
                const float* q0p = reinterpret_cast<const float*>(&q0);
                const float* q1p = reinterpret_cast<const float*>(&q1);
                half8 ah2;
                #pragma unroll
                for (int j = 0; j < 8; ++j)
                    ah2[j] = (_Float16)((j < 4) ? q0p[j] : q1p[j - 4]);
                half8 bv = *reinterpret_cast<const half8*>(sVf + (bl * 4 + kt) * 512 + lane * 8);
                if (kt & 1) T1 = __builtin_amdgcn_mfma_f32_16x16x32_f16(ah2, bv, T1, 0, 0, 0);
                else        T0 = __builtin_amdgcn_mfma_f32_16x16x32_f16(ah2, bv, T0, 0, 0, 0);
            }

            // G-weight (T C-layout: col=lane&15=cm, row=quad*4+reg=a-local)
            const int comp = (m >= 1 && m <= 8) ? (m - 1) : 0;
            float ps[4];
            #pragma unroll
            for (int reg = 0; reg < 4; ++reg) {
                const int row = quad * 4 + reg;
                const float Tv = T0[reg] + T1[reg];
                const float yv = sYw[wv][p][row][comp];
                const float g = (m == 0) ? 1.0f : ((m <= 8) ? yv : 0.0f);
                ps[reg] = Tv * g;
            }
            #pragma unroll
            for (int off = 1; off < 16; off <<= 1)
                #pragma unroll
                for (int reg = 0; reg < 4; ++reg)
                    ps[reg] += __shfl_xor(ps[reg], off);
            #pragma unroll
            for (int reg = 0; reg < 4; ++reg) outAcc[reg] += ps[reg];
        }
    }

    // ---- write partial[z][bg][a]: lanes m==0 hold a = wv*16 + quad*4 + reg ----
    if (m == 0) {
        float4 st;
        st.x = outAcc[0]; st.y = outAcc[1]; st.z = outAcc[2]; st.w = outAcc[3];
        *reinterpret_cast<float4*>(partial + ((size_t)(z * 8 + bg)) * 64 + wv * 16 + quad * 4) = st;
    }
}

// ---------------------------------------------------------------------------
// finalize: out[z,a] = sp( (sum_bg partial) / sqrt(n_atoms) ) * mask
// ---------------------------------------------------------------------------
__global__ __launch_bounds__(64, 8)
void finalize(const float* __restrict__ partial, const float* __restrict__ mask,
              float* __restrict__ out) {
    const int z = blockIdx.x, a = threadIdx.x;
    const float mk = mask[z * 64 + a];
    float s = mk;
    #pragma unroll
    for (int off = 32; off > 0; off >>= 1) s += __shfl_xor(s, off);
    const float inv = rsqrtf(s);
    float acc = 0.f;
    #pragma unroll
    for (int bg = 0; bg < 8; ++bg)
        acc += partial[((size_t)(z * 8 + bg)) * 64 + a];
    out[z * 64 + a] = sp_f(acc * inv) * mk;
}

extern "C" void kernel_launch(void* const* d_in, const int* in_sizes, int n_in,
                              void* d_out, int out_size, void* d_ws, size_t ws_size,
                              hipStream_t stream) {
    const float* rep  = (const float*)d_in[0];
    const float* geom = (const float*)d_in[1];
    const float* mask = (const float*)d_in[2];
    const float* W1   = (const float*)d_in[3];
    const float* W2   = (const float*)d_in[4];
    const float* W3   = (const float*)d_in[5];
    float* out = (float*)d_out;

    _Float16* w2f = (_Float16*)d_ws;                       // 32768 B
    float* partial = (float*)((char*)d_ws + 32768);        // 512*64*4 = 131072 B
    // ws_size >= 33.6 MB proven in round 4 (big path executed) — no fallback needed.

    w2half<<<16, 256, 0, stream>>>(W2, w2f);
    pair4<<<dim3(8, 64), 256, 0, stream>>>(rep, geom, W1, W3, w2f, partial);
    finalize<<<64, 64, 0, stream>>>(partial, mask, out);
}